// Round 13
// baseline (1159.769 us; speedup 1.0000x reference)
//
#include <hip/hip_runtime.h>
#include <hip/hip_cooperative_groups.h>
#include <cstdint>
#include <cstddef>

namespace cg = cooperative_groups;

// ---------------------------------------------------------------------------
// GCN: h = elu(D^-1/2 (A+I) D^-1/2 (h W) + b) x3, mean-pool, MLP head.
// R13: ONE cooperative persistent kernel (12 dispatches -> 2). R12 analysis:
// tail (237 us) is dominated by ~10 us/dispatch launch overhead, and gather
// (3x44 us) is at the random-row service floor. Phases separated by
// grid.sync(): scatter -> build(+cvtW+poolzero) -> [gemm|gather]x3 -> pool ->
// classifier(+cnt). All inner loops verbatim from R10-R12.
// ---------------------------------------------------------------------------

#define SUBCAP 512   // per-(bucket,XCD) capacity: mean 256, +16 sigma
#define CSRCAP 4608  // per-bucket csr region: 4096 max edges + ceil4 padding
#define TILE 4096    // edges per scatter tile

typedef __attribute__((ext_vector_type(8))) short short8;   // 8 bf16 = 4 VGPRs
typedef __attribute__((ext_vector_type(4))) float f32x4;
typedef __attribute__((ext_vector_type(2))) _Float16 h16x2; // packed f16 pair

__device__ __forceinline__ float bf2f(uint32_t u) {
  return __uint_as_float(u << 16);
}
__device__ __forceinline__ uint32_t f2bf(float f) {  // round-to-nearest-even
  uint32_t x = __float_as_uint(f);
  return (x + 0x7FFFu + ((x >> 16) & 1u)) >> 16;
}

union H16 { _Float16 h; uint16_t u; };
union H2U { h16x2 h; uint32_t u; };

// f32 -> e5m2 byte (RNE via f16 then RNE-truncate mantissa to 2 bits)
__device__ __forceinline__ uint32_t f2e5m2(float f) {
  f = fminf(fmaxf(f, -30000.f), 30000.f);
  H16 cv;
  cv.h = (_Float16)f;
  uint32_t h = cv.u;
  uint32_t r = h + 0x7Fu + ((h >> 8) & 1u);
  return (r >> 8) & 0xFFu;
}

// e5m2 byte -> f32 (exact: e5m2 is truncated f16)
__device__ __forceinline__ float e5m2f(uint32_t b) {
  H16 cv;
  cv.u = (uint16_t)(b << 8);
  return (float)cv.h;
}

// v_perm packs 2 e5m2 bytes -> 2 f16 lanes; v_pk_add_f16 accumulates.
__device__ __forceinline__ void acc_pk(uint32_t u, h16x2& a01, h16x2& a23) {
  H2U p01, p23;
  p01.u = __builtin_amdgcn_perm(u, 0u, 0x05010400u);  // (b0<<8)|(b1<<24)
  p23.u = __builtin_amdgcn_perm(u, 0u, 0x07010600u);  // (b2<<8)|(b3<<24)
  a01 += p01.h;
  a23 += p23.h;
}

// ---------------------------------------------------------------------------
// The persistent cooperative kernel. 34,816 B static LDS -> 4 blocks/CU.
// ---------------------------------------------------------------------------
__global__ __launch_bounds__(256, 4) void mega(
    const float* __restrict__ x, const int* __restrict__ src,
    const int* __restrict__ dst,
    const float* __restrict__ W1, const float* __restrict__ W2,
    const float* __restrict__ W3,
    const float* __restrict__ b1, const float* __restrict__ b2,
    const float* __restrict__ b3,
    const float* __restrict__ Wc1, const float* __restrict__ bc1,
    const float* __restrict__ Wc2, const float* __restrict__ bc2,
    const int* __restrict__ batch,
    int* __restrict__ bcur, uint32_t* __restrict__ ebuf,
    int* __restrict__ deg, float* __restrict__ dinv,
    int* __restrict__ offs, int* __restrict__ csr,
    uint16_t* __restrict__ WT, uint8_t* __restrict__ tab,
    uint16_t* __restrict__ bufO, float* __restrict__ pool,
    float* __restrict__ outp,
    int n, int nE, int nbuk) {
  cg::grid_group grid = cg::this_grid();
  __shared__ __align__(16) uint8_t smem[128 * 136 * 2];  // 34,816 B, phase-aliased
  int t = threadIdx.x;
  int bid = blockIdx.x, G = gridDim.x;

  // ---- Phase S: XCD-partitioned block-aggregated scatter + W cvt + pool zero
  {
    uint32_t xcc;
    asm("s_getreg_b32 %0, hwreg(HW_REG_XCC_ID)" : "=s"(xcc));  // wave-uniform
    int* lhist = (int*)smem;
    int* gbase = lhist + 1024;
    int ntile = (nE + TILE - 1) / TILE;
    for (int tile = bid; tile < ntile; tile += G) {
      for (int i = t; i < nbuk; i += 256) lhist[i] = 0;
      __syncthreads();
      int e0 = tile * TILE;
      int myd[16], mys[16], myrank[16];
#pragma unroll
      for (int j = 0; j < 16; ++j) {
        int e = e0 + t + j * 256;  // coalesced
        if (e < nE) {
          int d = dst[e];
          myd[j] = d;
          mys[j] = src[e];
          myrank[j] = atomicAdd(&lhist[d >> 7], 1);
        } else {
          myd[j] = -1;
        }
      }
      __syncthreads();
      for (int i = t; i < nbuk; i += 256) {
        int c = lhist[i];
        gbase[i] = c ? atomicAdd(&bcur[((i << 3) | (int)xcc) * 16], c) : 0;
      }
      __syncthreads();
#pragma unroll
      for (int j = 0; j < 16; ++j) {
        if (myd[j] >= 0) {
          int b = myd[j] >> 7;
          int pos = gbase[b] + myrank[j];
          if (pos < SUBCAP) {
            int sub = (b << 3) | (int)xcc;
            ebuf[(size_t)sub * SUBCAP + pos] =
                ((uint32_t)(myd[j] & 127) << 20) | (uint32_t)mys[j];
          }
        }
      }
      __syncthreads();
    }
    // W1,W2,W3 fp32 [k][nn] -> WT bf16 [w][nn][k]  (stride-G, any G)
    for (int id = bid * 256 + t; id < 3 * 16384; id += G * 256) {
      int w = id >> 14;
      int rem = id & 16383;
      int k = rem >> 7, nn = rem & 127;
      const float* W = (w == 0) ? W1 : ((w == 1) ? W2 : W3);
      WT[w * 16384 + nn * 128 + k] = (uint16_t)f2bf(W[k * 128 + nn]);
    }
    for (int id = bid * 256 + t; id < 64 * 128; id += G * 256) pool[id] = 0.f;
  }
  grid.sync();

  // ---- Phase B: fused hist + prefix + fill (4-aligned csr segments)
  {
    int* hist = (int*)smem;
    int* pre = hist + 128;
    int* lcur = pre + 128;
    for (int b = bid; b < nbuk; b += G) {
      int base = b << 7;
      if (t < 128) hist[t] = 0;
      __syncthreads();
      int cnts[8];
#pragma unroll
      for (int x2 = 0; x2 < 8; ++x2) {
        int sub = (b << 3) | x2;
        int cnt = min(bcur[sub * 16], SUBCAP);
        cnts[x2] = cnt;
        const uint32_t* eb = ebuf + (size_t)sub * SUBCAP;
        for (int e = t; e < cnt; e += 256) atomicAdd(&hist[eb[e] >> 20], 1);
      }
      __syncthreads();
      if (t < 128) pre[t] = (hist[t] + 3) & ~3;  // ceil4 region sizes
      __syncthreads();
      for (int d = 1; d < 128; d <<= 1) {  // inclusive scan
        int v = (t >= d && t < 128) ? pre[t - d] : 0;
        __syncthreads();
        if (t < 128) pre[t] += v;
        __syncthreads();
      }
      if (t < 128) {
        int dg = hist[t];
        int start = b * CSRCAP + pre[t] - ((dg + 3) & ~3);  // 4-aligned
        lcur[t] = start;
        if (base + t < n) {
          deg[base + t] = dg;
          dinv[base + t] = rsqrtf((float)(dg + 1));  // +1 self-loop
          offs[base + t] = start;
        }
      }
      __syncthreads();
#pragma unroll
      for (int x2 = 0; x2 < 8; ++x2) {
        int sub = (b << 3) | x2;
        int cnt = cnts[x2];
        const uint32_t* eb = ebuf + (size_t)sub * SUBCAP;
        for (int e = t; e < cnt; e += 256) {
          uint32_t ed = eb[e];
          int pos = atomicAdd(&lcur[ed >> 20], 1);
          csr[pos] = (int)((ed & 0xFFFFFu) << 7);  // byte offset into fp8 table
        }
      }
      __syncthreads();
    }
  }
  grid.sync();

  // ---- 3 layers: [gemm -> sync -> gather -> sync]
  uint16_t* sW = (uint16_t*)smem;
  int ntiles = (n + 63) / 64;
  int nchunk = (n + 7) / 8;
  const float* bs0[3] = {b1, b2, b3};
  for (int l = 0; l < 3; ++l) {
    const uint16_t* WTb = WT + l * 16384;
    // gemm: bf16 (or fp32 layer 0) in, fp8(e5m2) dinv-scaled table out
    for (int tile = bid; tile < ntiles; tile += G) {
      __syncthreads();
#pragma unroll
      for (int i = 0; i < 8; ++i) {
        int j = t + i * 256;
        int r = j >> 4, c = j & 15;
        float4 v = ((const float4*)WTb)[j];
        *(float4*)(sW + r * 136 + c * 8) = v;
      }
      __syncthreads();
      int wave = t >> 6, lane = t & 63;
      int quad = lane >> 4, l15 = lane & 15;
      int m = tile * 64 + wave * 16 + l15;
      int mm = min(m, n - 1);
      short8 a[4];
#pragma unroll
      for (int kc = 0; kc < 4; ++kc) {
        if (l == 0) {
          const float* p = x + (size_t)mm * 128 + kc * 32 + quad * 8;
          float4 lo = *(const float4*)p;
          float4 hi = *(const float4*)(p + 4);
          a[kc] = (short8){(short)f2bf(lo.x), (short)f2bf(lo.y),
                           (short)f2bf(lo.z), (short)f2bf(lo.w),
                           (short)f2bf(hi.x), (short)f2bf(hi.y),
                           (short)f2bf(hi.z), (short)f2bf(hi.w)};
        } else {
          a[kc] = *(const short8*)(bufO + (size_t)mm * 128 + kc * 32 + quad * 8);
        }
      }
      f32x4 acc[8];
#pragma unroll
      for (int nn = 0; nn < 8; ++nn) acc[nn] = (f32x4){0.f, 0.f, 0.f, 0.f};
#pragma unroll
      for (int nn = 0; nn < 8; ++nn) {
        int nrow = nn * 16 + l15;
#pragma unroll
        for (int kc = 0; kc < 4; ++kc) {
          short8 bfr = *(const short8*)(sW + nrow * 136 + kc * 32 + quad * 8);
          acc[nn] = __builtin_amdgcn_mfma_f32_16x16x32_bf16(a[kc], bfr, acc[nn], 0, 0, 0);
        }
      }
      int mrow = tile * 64 + wave * 16 + quad * 4;
#pragma unroll
      for (int r = 0; r < 4; ++r) {
        int row = mrow + r;
        if (row < n) {
          float dn = dinv[row];
#pragma unroll
          for (int nn = 0; nn < 8; ++nn) {
            tab[(size_t)row * 128 + nn * 16 + l15] = (uint8_t)f2e5m2(acc[nn][r] * dn);
          }
        }
      }
    }
    grid.sync();
    // gather: half-wave per node, int4 csr, packed-f16 accumulate
    const float* bvec = bs0[l];
    for (int chunk = bid; chunk < nchunk; chunk += G) {
      int node = chunk * 8 + (t >> 5);
      if (node < n) {
        int l2 = t & 31;
        int c = l2 * 4;
        const uint8_t* tabc = tab + c;
        int e0 = offs[node];  // 4-aligned by construction
        int e1 = e0 + deg[node];
        h16x2 a01 = (h16x2){(_Float16)0.f, (_Float16)0.f};
        h16x2 a23 = (h16x2){(_Float16)0.f, (_Float16)0.f};
        int e = e0;
        for (; e + 7 < e1; e += 8) {
          int4 ca = *(const int4*)(csr + e);
          int4 cb = *(const int4*)(csr + e + 4);
          uint32_t u[8];
          u[0] = *(const uint32_t*)(tabc + ca.x);
          u[1] = *(const uint32_t*)(tabc + ca.y);
          u[2] = *(const uint32_t*)(tabc + ca.z);
          u[3] = *(const uint32_t*)(tabc + ca.w);
          u[4] = *(const uint32_t*)(tabc + cb.x);
          u[5] = *(const uint32_t*)(tabc + cb.y);
          u[6] = *(const uint32_t*)(tabc + cb.z);
          u[7] = *(const uint32_t*)(tabc + cb.w);
#pragma unroll
          for (int j = 0; j < 8; ++j) acc_pk(u[j], a01, a23);
        }
        if (e + 3 < e1) {
          int4 ca = *(const int4*)(csr + e);
          uint32_t u[4];
          u[0] = *(const uint32_t*)(tabc + ca.x);
          u[1] = *(const uint32_t*)(tabc + ca.y);
          u[2] = *(const uint32_t*)(tabc + ca.z);
          u[3] = *(const uint32_t*)(tabc + ca.w);
#pragma unroll
          for (int j = 0; j < 4; ++j) acc_pk(u[j], a01, a23);
          e += 4;
        }
        for (; e < e1; ++e) acc_pk(*(const uint32_t*)(tabc + csr[e]), a01, a23);

        float a0 = (float)a01.x, a1 = (float)a01.y;
        float a2 = (float)a23.x, a3 = (float)a23.y;
        float dn = dinv[node];
        uint32_t uh = *(const uint32_t*)(tabc + node * 128);  // self-loop
        float4 bb = *(const float4*)(bvec + c);
        float o0 = (a0 + e5m2f(uh & 0xFFu)) * dn + bb.x;
        float o1 = (a1 + e5m2f((uh >> 8) & 0xFFu)) * dn + bb.y;
        float o2 = (a2 + e5m2f((uh >> 16) & 0xFFu)) * dn + bb.z;
        float o3 = (a3 + e5m2f(uh >> 24)) * dn + bb.w;
        o0 = o0 > 0.f ? o0 : expm1f(o0);
        o1 = o1 > 0.f ? o1 : expm1f(o1);
        o2 = o2 > 0.f ? o2 : expm1f(o2);
        o3 = o3 > 0.f ? o3 : expm1f(o3);
        uint2 po;
        po.x = f2bf(o0) | (f2bf(o1) << 16);
        po.y = f2bf(o2) | (f2bf(o3) << 16);
        *(uint2*)(bufO + (size_t)node * 128 + c) = po;
      }
    }
    grid.sync();
  }

  // ---- Phase P: mean-pool accumulate (batch sorted; segmented, flush on change)
  {
    int* sb = (int*)smem;  // 128 ints
    int tsub = t & 127, grp = t >> 7;
    int npc = (n + 127) / 128;
    for (int c = bid; c < npc; c += G) {
      __syncthreads();
      int i0 = c * 128 + grp * 64;
      if (tsub < 64) {
        int ii = c * 128 + grp * 64 + tsub;
        sb[grp * 64 + tsub] = (ii < n) ? batch[ii] : -1;
      }
      __syncthreads();
      if (i0 < n) {
        int iend = min(i0 + 64, n);
        float acc = 0.f;
        int cur = sb[grp * 64];
        for (int i = i0; i < iend; ++i) {
          int g2 = sb[grp * 64 + (i - i0)];
          if (g2 != cur) {
            atomicAdd(&pool[cur * 128 + tsub], acc);
            acc = 0.f;
            cur = g2;
          }
          acc += bf2f((uint32_t)bufO[(size_t)i * 128 + tsub]);
        }
        atomicAdd(&pool[cur * 128 + tsub], acc);
      }
    }
  }
  grid.sync();

  // ---- Phase C: cnt (binary search) + classifier, block 0 only
  if (bid == 0) {
    uint16_t* sg = (uint16_t*)smem;            // 64x128 bf16 = 16 KB
    float* sz = (float*)(smem + 16384);        // 64x64 f32  = 16 KB
    int* scnt = (int*)(smem + 32768);          // 64 ints
    if (t < 64) {
      auto lbf = [&](int v) {
        int lo = 0, hi = n;
        while (lo < hi) {
          int mid = (lo + hi) >> 1;
          if (batch[mid] < v) lo = mid + 1; else hi = mid;
        }
        return lo;
      };
      scnt[t] = lbf(t + 1) - lbf(t);
    }
    __syncthreads();
    for (int i = t; i < 64 * 128; i += 256) {
      int gi = i >> 7;
      float c = (float)max(scnt[gi], 1);
      sg[i] = (uint16_t)f2bf(pool[i] / c);
    }
    __syncthreads();
    for (int i = t; i < 64 * 64; i += 256) {
      int gi = i >> 6, j = i & 63;
      float acc = bc1[j];
      for (int k = 0; k < 128; ++k)
        acc += bf2f((uint32_t)sg[gi * 128 + k]) * Wc1[k * 64 + j];
      sz[i] = fmaxf(acc, 0.f);
    }
    __syncthreads();
    if (t < 64) {
      float acc = bc2[0];
      for (int j = 0; j < 64; ++j) acc += sz[t * 64 + j] * Wc2[j];
      outp[t] = 1.f / (1.f + expf(-acc));
    }
  }
}

extern "C" void kernel_launch(void* const* d_in, const int* in_sizes, int n_in,
                              void* d_out, int out_size, void* d_ws, size_t ws_size,
                              hipStream_t stream) {
  const float* x   = (const float*)d_in[0];
  const int* ei    = (const int*)d_in[1];
  const int* batch = (const int*)d_in[2];
  const float* W1  = (const float*)d_in[3];
  const float* b1  = (const float*)d_in[4];
  const float* W2  = (const float*)d_in[5];
  const float* b2  = (const float*)d_in[6];
  const float* W3  = (const float*)d_in[7];
  const float* b3  = (const float*)d_in[8];
  const float* Wc1 = (const float*)d_in[9];
  const float* bc1 = (const float*)d_in[10];
  const float* Wc2 = (const float*)d_in[11];
  const float* bc2 = (const float*)d_in[12];

  int n  = in_sizes[2];
  int nE = in_sizes[1] / 2;
  const int* src = ei;
  const int* dst = ei + nE;
  int nbuk = (n + 127) >> 7;  // 128-node dst buckets

  // Workspace (~68 MB). All segment element counts multiples of 4.
  uint8_t*  tab  = (uint8_t*)d_ws;                      // fp8 table [n*128]
  uint16_t* bufO = (uint16_t*)(tab + (size_t)n * 128);  // bf16 layer buf [n*128]
  float* dinv    = (float*)(bufO + (size_t)n * 128);
  int*   deg     = (int*)(dinv + n);
  int*   offs    = deg + n;                             // [n+4]
  int*   bcur    = offs + n + 4;                        // [nbuk*8*16] padded
  int*   csr     = bcur + nbuk * 8 * 16;                // [nbuk*CSRCAP]
  uint32_t* ebuf = (uint32_t*)(csr + (size_t)nbuk * CSRCAP);  // [nbuk*8*SUBCAP]
  uint16_t* WT   = (uint16_t*)(ebuf + (size_t)nbuk * 8 * SUBCAP);
  float* pool    = (float*)(WT + 3 * 16384);
  float* outp    = (float*)d_out;

  hipMemsetAsync(bcur, 0, (size_t)nbuk * 8 * 16 * sizeof(int), stream);

  int bpc = 0;
  hipOccupancyMaxActiveBlocksPerMultiprocessor(&bpc, (const void*)mega, 256, 0);
  if (bpc < 1) bpc = 1;
  int G = bpc * 256;  // 256 CUs on MI355X; co-resident by construction

  void* args[] = {
      (void*)&x, (void*)&src, (void*)&dst,
      (void*)&W1, (void*)&W2, (void*)&W3,
      (void*)&b1, (void*)&b2, (void*)&b3,
      (void*)&Wc1, (void*)&bc1, (void*)&Wc2, (void*)&bc2,
      (void*)&batch,
      (void*)&bcur, (void*)&ebuf, (void*)&deg, (void*)&dinv,
      (void*)&offs, (void*)&csr,
      (void*)&WT, (void*)&tab, (void*)&bufO, (void*)&pool, (void*)&outp,
      (void*)&n, (void*)&nE, (void*)&nbuk};
  hipLaunchCooperativeKernel((const void*)mega, dim3(G), dim3(256), args, 0, stream);
}

// Round 14
// 374.342 us; speedup vs baseline: 3.0982x; 3.0982x over previous
//
#include <hip/hip_runtime.h>
#include <cstdint>
#include <cstddef>

// ---------------------------------------------------------------------------
// GCN: h = elu(D^-1/2 (A+I) D^-1/2 (h W) + b) x3, mean-pool, MLP head.
// R14: REVERT of R13 (cooperative mega-kernel: grid.sync() cost ~80 us/sync,
// +790 us total — persistent-kernel path abandoned). Back to R12 structure,
// minus 3 dispatches via safe fusions:
//  - cvt_wt + pool-zero folded into bucket_build (grid-stride side jobs),
//  - cnt binary-search folded into classifier_kernel (R13 phase C, proven).
// 13 -> 10 dispatches. All hot loops byte-identical to R12.
// ---------------------------------------------------------------------------

#define SUBCAP 512   // per-(bucket,XCD) capacity: mean 256, +16 sigma
#define CSRCAP 4608  // per-bucket csr region: 4096 max edges + ceil4 padding
#define TILE 4096    // edges per scatter block

typedef __attribute__((ext_vector_type(8))) short short8;   // 8 bf16 = 4 VGPRs
typedef __attribute__((ext_vector_type(4))) float f32x4;
typedef __attribute__((ext_vector_type(2))) _Float16 h16x2; // packed f16 pair

__device__ __forceinline__ float bf2f(uint32_t u) {
  return __uint_as_float(u << 16);
}
__device__ __forceinline__ uint32_t f2bf(float f) {  // round-to-nearest-even
  uint32_t x = __float_as_uint(f);
  return (x + 0x7FFFu + ((x >> 16) & 1u)) >> 16;
}

union H16 { _Float16 h; uint16_t u; };
union H2U { h16x2 h; uint32_t u; };

// f32 -> e5m2 byte (RNE via f16 then RNE-truncate mantissa to 2 bits)
__device__ __forceinline__ uint32_t f2e5m2(float f) {
  f = fminf(fmaxf(f, -30000.f), 30000.f);
  H16 cv;
  cv.h = (_Float16)f;
  uint32_t h = cv.u;
  uint32_t r = h + 0x7Fu + ((h >> 8) & 1u);
  return (r >> 8) & 0xFFu;
}

// e5m2 byte -> f32 (exact: e5m2 is truncated f16)
__device__ __forceinline__ float e5m2f(uint32_t b) {
  H16 cv;
  cv.u = (uint16_t)(b << 8);
  return (float)cv.h;
}

// ---------------- CSR build ----------------

// Block-aggregated, XCD-partitioned scatter. 4096 edges/block. (R10)
__global__ __launch_bounds__(256) void bucket_scatter(const int* __restrict__ src,
                                                      const int* __restrict__ dst,
                                                      int* __restrict__ bcur,
                                                      uint32_t* __restrict__ ebuf,
                                                      int nE, int nbuk) {
  uint32_t xcc;
  asm("s_getreg_b32 %0, hwreg(HW_REG_XCC_ID)" : "=s"(xcc));  // 0..7, wave-uniform
  __shared__ int lhist[1024];
  __shared__ int gbase[1024];
  int t = threadIdx.x;
  for (int i = t; i < nbuk; i += 256) lhist[i] = 0;
  __syncthreads();

  int e0 = blockIdx.x * TILE;
  int myd[16], mys[16], myrank[16];
#pragma unroll
  for (int j = 0; j < 16; ++j) {
    int e = e0 + t + j * 256;  // coalesced
    if (e < nE) {
      int d = dst[e];
      myd[j] = d;
      mys[j] = src[e];
      myrank[j] = atomicAdd(&lhist[d >> 7], 1);  // returns old -> local rank
    } else {
      myd[j] = -1;
    }
  }
  __syncthreads();
  for (int i = t; i < nbuk; i += 256) {
    int c = lhist[i];
    gbase[i] = c ? atomicAdd(&bcur[((i << 3) | (int)xcc) * 16], c) : 0;
  }
  __syncthreads();
#pragma unroll
  for (int j = 0; j < 16; ++j) {
    if (myd[j] >= 0) {
      int b = myd[j] >> 7;
      int pos = gbase[b] + myrank[j];
      if (pos < SUBCAP) {
        int sub = (b << 3) | (int)xcc;
        ebuf[(size_t)sub * SUBCAP + pos] =
            ((uint32_t)(myd[j] & 127) << 20) | (uint32_t)mys[j];
      }
    }
  }
}

// Fused hist + prefix + fill (R12) + side jobs: W cvt, pool zero (R14).
__global__ __launch_bounds__(256) void bucket_build(const uint32_t* __restrict__ ebuf,
                                                    const int* __restrict__ bcur,
                                                    int* __restrict__ deg,
                                                    float* __restrict__ dinv,
                                                    int* __restrict__ offs,
                                                    int* __restrict__ csr,
                                                    const float* __restrict__ W1,
                                                    const float* __restrict__ W2,
                                                    const float* __restrict__ W3,
                                                    uint16_t* __restrict__ WT,
                                                    float* __restrict__ pool,
                                                    int n, int nbuk) {
  int b = blockIdx.x;
  int base = b << 7;
  __shared__ int hist[128];
  __shared__ int pre[128];
  __shared__ int lcur[128];
  int t = threadIdx.x;

  // Side job 1: W1,W2,W3 fp32 [k][nn] -> WT bf16 [w][nn][k]  (grid-stride)
  for (int id = b * 256 + t; id < 3 * 16384; id += nbuk * 256) {
    int w = id >> 14;
    int rem = id & 16383;
    int k = rem >> 7, nn = rem & 127;
    const float* W = (w == 0) ? W1 : ((w == 1) ? W2 : W3);
    WT[w * 16384 + nn * 128 + k] = (uint16_t)f2bf(W[k * 128 + nn]);
  }
  // Side job 2: zero pool
  for (int id = b * 256 + t; id < 64 * 128; id += nbuk * 256) pool[id] = 0.f;

  if (t < 128) hist[t] = 0;
  __syncthreads();
  int cnts[8];
#pragma unroll
  for (int x = 0; x < 8; ++x) {
    int sub = (b << 3) | x;
    int cnt = min(bcur[sub * 16], SUBCAP);
    cnts[x] = cnt;
    const uint32_t* eb = ebuf + (size_t)sub * SUBCAP;
    for (int e = t; e < cnt; e += 256) atomicAdd(&hist[eb[e] >> 20], 1);
  }
  __syncthreads();
  if (t < 128) pre[t] = (hist[t] + 3) & ~3;  // ceil4 region sizes
  __syncthreads();
  for (int d = 1; d < 128; d <<= 1) {  // inclusive scan
    int v = (t >= d && t < 128) ? pre[t - d] : 0;
    __syncthreads();
    if (t < 128) pre[t] += v;
    __syncthreads();
  }
  if (t < 128) {
    int dg = hist[t];
    int start = b * CSRCAP + pre[t] - ((dg + 3) & ~3);  // 4-aligned
    lcur[t] = start;
    if (base + t < n) {
      deg[base + t] = dg;
      dinv[base + t] = rsqrtf((float)(dg + 1));  // +1 self-loop
      offs[base + t] = start;
    }
  }
  __syncthreads();
#pragma unroll
  for (int x = 0; x < 8; ++x) {
    int sub = (b << 3) | x;
    int cnt = cnts[x];
    const uint32_t* eb = ebuf + (size_t)sub * SUBCAP;
    for (int e = t; e < cnt; e += 256) {
      uint32_t ed = eb[e];
      int pos = atomicAdd(&lcur[ed >> 20], 1);
      csr[pos] = (int)((ed & 0xFFFFFu) << 7);  // byte offset into fp8 table
    }
  }
}

// ---------------- MFMA GEMM: bf16/fp32 in, fp8(e5m2) table out ----------------

template <bool F32IN>
__global__ __launch_bounds__(256) void gemm_mfma(const uint16_t* __restrict__ Xb,
                                                 const float* __restrict__ X32,
                                                 const uint16_t* __restrict__ WTb,
                                                 const float* __restrict__ dinv,
                                                 uint8_t* __restrict__ tab, int n) {
  __shared__ uint16_t sW[128 * 136];
  int t = threadIdx.x;
#pragma unroll
  for (int i = 0; i < 8; ++i) {
    int j = t + i * 256;
    int r = j >> 4, c = j & 15;
    float4 v = ((const float4*)WTb)[j];
    *(float4*)(sW + r * 136 + c * 8) = v;
  }
  __syncthreads();

  int wave = t >> 6, lane = t & 63;
  int quad = lane >> 4, l15 = lane & 15;
  int m = blockIdx.x * 64 + wave * 16 + l15;
  int mm = min(m, n - 1);

  short8 a[4];
#pragma unroll
  for (int kc = 0; kc < 4; ++kc) {
    if constexpr (F32IN) {
      const float* p = X32 + (size_t)mm * 128 + kc * 32 + quad * 8;
      float4 lo = *(const float4*)p;
      float4 hi = *(const float4*)(p + 4);
      a[kc] = (short8){(short)f2bf(lo.x), (short)f2bf(lo.y),
                       (short)f2bf(lo.z), (short)f2bf(lo.w),
                       (short)f2bf(hi.x), (short)f2bf(hi.y),
                       (short)f2bf(hi.z), (short)f2bf(hi.w)};
    } else {
      a[kc] = *(const short8*)(Xb + (size_t)mm * 128 + kc * 32 + quad * 8);
    }
  }

  f32x4 acc[8];
#pragma unroll
  for (int nn = 0; nn < 8; ++nn) acc[nn] = (f32x4){0.f, 0.f, 0.f, 0.f};

#pragma unroll
  for (int nn = 0; nn < 8; ++nn) {
    int nrow = nn * 16 + l15;
#pragma unroll
    for (int kc = 0; kc < 4; ++kc) {
      short8 b = *(const short8*)(sW + nrow * 136 + kc * 32 + quad * 8);
      acc[nn] = __builtin_amdgcn_mfma_f32_16x16x32_bf16(a[kc], b, acc[nn], 0, 0, 0);
    }
  }

  int mrow = blockIdx.x * 64 + wave * 16 + quad * 4;
#pragma unroll
  for (int r = 0; r < 4; ++r) {
    int row = mrow + r;
    if (row < n) {
      float dn = dinv[row];
#pragma unroll
      for (int nn = 0; nn < 8; ++nn) {
        tab[(size_t)row * 128 + nn * 16 + l15] = (uint8_t)f2e5m2(acc[nn][r] * dn);
      }
    }
  }
}

// ---------------- gather: half-wave per node, packed f16, int4 csr ----------------

__device__ __forceinline__ void acc_pk(uint32_t u, h16x2& a01, h16x2& a23) {
  H2U p01, p23;
  p01.u = __builtin_amdgcn_perm(u, 0u, 0x05010400u);  // (b0<<8)|(b1<<24)
  p23.u = __builtin_amdgcn_perm(u, 0u, 0x07010600u);  // (b2<<8)|(b3<<24)
  a01 += p01.h;
  a23 += p23.h;
}

__global__ __launch_bounds__(256) void gather_fused(const uint8_t* __restrict__ tab,
                                                    const int* __restrict__ csr,
                                                    const int* __restrict__ offs,
                                                    const int* __restrict__ deg,
                                                    const float* __restrict__ dinv,
                                                    const float* __restrict__ b,
                                                    uint16_t* __restrict__ out, int n) {
  int node = blockIdx.x * 8 + (threadIdx.x >> 5);
  if (node >= n) return;
  int l = threadIdx.x & 31;
  int c = l * 4;  // feature/byte offset within row
  const uint8_t* tabc = tab + c;
  int e0 = offs[node];             // 4-aligned by construction
  int e1 = e0 + deg[node];
  h16x2 a01 = (h16x2){(_Float16)0.f, (_Float16)0.f};
  h16x2 a23 = (h16x2){(_Float16)0.f, (_Float16)0.f};

  int e = e0;
  for (; e + 7 < e1; e += 8) {
    int4 ca = *(const int4*)(csr + e);
    int4 cb = *(const int4*)(csr + e + 4);
    uint32_t u[8];
    u[0] = *(const uint32_t*)(tabc + ca.x);
    u[1] = *(const uint32_t*)(tabc + ca.y);
    u[2] = *(const uint32_t*)(tabc + ca.z);
    u[3] = *(const uint32_t*)(tabc + ca.w);
    u[4] = *(const uint32_t*)(tabc + cb.x);
    u[5] = *(const uint32_t*)(tabc + cb.y);
    u[6] = *(const uint32_t*)(tabc + cb.z);
    u[7] = *(const uint32_t*)(tabc + cb.w);
#pragma unroll
    for (int j = 0; j < 8; ++j) acc_pk(u[j], a01, a23);
  }
  if (e + 3 < e1) {
    int4 ca = *(const int4*)(csr + e);
    uint32_t u[4];
    u[0] = *(const uint32_t*)(tabc + ca.x);
    u[1] = *(const uint32_t*)(tabc + ca.y);
    u[2] = *(const uint32_t*)(tabc + ca.z);
    u[3] = *(const uint32_t*)(tabc + ca.w);
#pragma unroll
    for (int j = 0; j < 4; ++j) acc_pk(u[j], a01, a23);
    e += 4;
  }
  for (; e < e1; ++e) acc_pk(*(const uint32_t*)(tabc + csr[e]), a01, a23);

  float a0 = (float)a01.x, a1 = (float)a01.y;
  float a2 = (float)a23.x, a3 = (float)a23.y;

  float dn = dinv[node];
  uint32_t uh = *(const uint32_t*)(tabc + node * 128);  // self-loop
  float4 bb = *(const float4*)(b + c);
  float o0 = (a0 + e5m2f(uh & 0xFFu)) * dn + bb.x;
  float o1 = (a1 + e5m2f((uh >> 8) & 0xFFu)) * dn + bb.y;
  float o2 = (a2 + e5m2f((uh >> 16) & 0xFFu)) * dn + bb.z;
  float o3 = (a3 + e5m2f(uh >> 24)) * dn + bb.w;
  o0 = o0 > 0.f ? o0 : expm1f(o0);
  o1 = o1 > 0.f ? o1 : expm1f(o1);
  o2 = o2 > 0.f ? o2 : expm1f(o2);
  o3 = o3 > 0.f ? o3 : expm1f(o3);
  uint2 po;
  po.x = f2bf(o0) | (f2bf(o1) << 16);
  po.y = f2bf(o2) | (f2bf(o3) << 16);
  *(uint2*)(out + (size_t)node * 128 + c) = po;
}

// ---------------- pooling + head ----------------

__global__ __launch_bounds__(128) void pool_kernel(const uint16_t* __restrict__ h,
                                                   const int* __restrict__ batch,
                                                   float* __restrict__ pool, int n) {
  int f = threadIdx.x;
  int i0 = blockIdx.x * 64;
  int iend = min(i0 + 64, n);
  __shared__ int sb[64];
  if (threadIdx.x < 64 && i0 + threadIdx.x < n) sb[threadIdx.x] = batch[i0 + threadIdx.x];
  __syncthreads();
  float acc = 0.f;
  int cur = sb[0];
  for (int i = i0; i < iend; ++i) {
    int g = sb[i - i0];
    if (g != cur) {
      atomicAdd(&pool[cur * 128 + f], acc);
      acc = 0.f;
      cur = g;
    }
    acc += bf2f((uint32_t)h[(size_t)i * 128 + f]);
  }
  atomicAdd(&pool[cur * 128 + f], acc);
}

// Classifier with cnt (binary search on sorted batch) folded in (R13 phase C).
__global__ __launch_bounds__(256) void classifier_kernel(const float* __restrict__ pool,
                                                         const int* __restrict__ batch,
                                                         const float* __restrict__ Wc1,
                                                         const float* __restrict__ bc1,
                                                         const float* __restrict__ Wc2,
                                                         const float* __restrict__ bc2,
                                                         float* __restrict__ out, int n) {
  __shared__ float g[64 * 128];
  __shared__ float z[64 * 64];
  __shared__ int scnt[64];
  int t = threadIdx.x;
  if (t < 64) {
    auto lbf = [&](int v) {
      int lo = 0, hi = n;
      while (lo < hi) {
        int mid = (lo + hi) >> 1;
        if (batch[mid] < v) lo = mid + 1; else hi = mid;
      }
      return lo;
    };
    scnt[t] = lbf(t + 1) - lbf(t);
  }
  __syncthreads();
  for (int i = t; i < 64 * 128; i += 256) {
    int gi = i >> 7;
    float c = (float)max(scnt[gi], 1);
    g[i] = pool[i] / c;
  }
  __syncthreads();
  for (int i = t; i < 64 * 64; i += 256) {
    int gi = i >> 6, j = i & 63;
    float acc = bc1[j];
    for (int k = 0; k < 128; ++k) acc += g[gi * 128 + k] * Wc1[k * 64 + j];
    z[i] = fmaxf(acc, 0.f);
  }
  __syncthreads();
  if (t < 64) {
    float acc = bc2[0];
    for (int j = 0; j < 64; ++j) acc += z[t * 64 + j] * Wc2[j];
    out[t] = 1.f / (1.f + expf(-acc));
  }
}

extern "C" void kernel_launch(void* const* d_in, const int* in_sizes, int n_in,
                              void* d_out, int out_size, void* d_ws, size_t ws_size,
                              hipStream_t stream) {
  const float* x   = (const float*)d_in[0];
  const int* ei    = (const int*)d_in[1];
  const int* batch = (const int*)d_in[2];
  const float* W1  = (const float*)d_in[3];
  const float* b1  = (const float*)d_in[4];
  const float* W2  = (const float*)d_in[5];
  const float* b2  = (const float*)d_in[6];
  const float* W3  = (const float*)d_in[7];
  const float* b3  = (const float*)d_in[8];
  const float* Wc1 = (const float*)d_in[9];
  const float* bc1 = (const float*)d_in[10];
  const float* Wc2 = (const float*)d_in[11];
  const float* bc2 = (const float*)d_in[12];

  int n  = in_sizes[2];
  int nE = in_sizes[1] / 2;
  const int* src = ei;
  const int* dst = ei + nE;
  int nbuk = (n + 127) >> 7;  // 128-node dst buckets

  // Workspace (~68 MB). All segment element counts multiples of 4.
  uint8_t*  tab  = (uint8_t*)d_ws;                      // fp8 table [n*128]
  uint16_t* bufO = (uint16_t*)(tab + (size_t)n * 128);  // bf16 layer buf [n*128]
  float* dinv    = (float*)(bufO + (size_t)n * 128);
  int*   deg     = (int*)(dinv + n);
  int*   offs    = deg + n;                             // [n+4]
  int*   bcur    = offs + n + 4;                        // [nbuk*8*16] padded
  int*   csr     = bcur + nbuk * 8 * 16;                // [nbuk*CSRCAP]
  uint32_t* ebuf = (uint32_t*)(csr + (size_t)nbuk * CSRCAP);  // [nbuk*8*SUBCAP]
  uint16_t* WT   = (uint16_t*)(ebuf + (size_t)nbuk * 8 * SUBCAP);
  float* pool    = (float*)(WT + 3 * 16384);
  float* out     = (float*)d_out;

  hipMemsetAsync(bcur, 0, (size_t)nbuk * 8 * 16 * sizeof(int), stream);
  bucket_scatter<<<(nE + TILE - 1) / TILE, 256, 0, stream>>>(src, dst, bcur, ebuf, nE, nbuk);
  bucket_build<<<nbuk, 256, 0, stream>>>(ebuf, bcur, deg, dinv, offs, csr,
                                         W1, W2, W3, WT, pool, n, nbuk);

  const float* bs[3] = {b1, b2, b3};
  for (int l = 0; l < 3; ++l) {
    if (l == 0)
      gemm_mfma<true><<<(n + 63) / 64, 256, 0, stream>>>(nullptr, x, WT, dinv, tab, n);
    else
      gemm_mfma<false><<<(n + 63) / 64, 256, 0, stream>>>(bufO, nullptr, WT + l * 16384, dinv, tab, n);
    gather_fused<<<(n + 7) / 8, 256, 0, stream>>>(tab, csr, offs, deg, dinv, bs[l], bufO, n);
  }

  pool_kernel<<<(n + 63) / 64, 128, 0, stream>>>(bufO, batch, pool, n);
  classifier_kernel<<<1, 256, 0, stream>>>(pool, batch, Wc1, bc1, Wc2, bc2, out, n);
}

// Round 15
// 347.982 us; speedup vs baseline: 3.3328x; 1.0758x over previous
//
#include <hip/hip_runtime.h>
#include <cstdint>
#include <cstddef>

// ---------------------------------------------------------------------------
// GCN: h = elu(D^-1/2 (A+I) D^-1/2 (h W) + b) x3, mean-pool, MLP head.
// R15: classifier parallelized. R14 profile showed classifier_kernel at 47 us
// (single block, 1 CU, latency-bound on Wc1 global reads). The head is
// independent per graph: one wave per graph (64 blocks x 64 thr), coalesced
// Wc1 reads, shfl-reduce logit. Everything else identical to R14/R12.
// ---------------------------------------------------------------------------

#define SUBCAP 512   // per-(bucket,XCD) capacity: mean 256, +16 sigma
#define CSRCAP 4608  // per-bucket csr region: 4096 max edges + ceil4 padding
#define TILE 4096    // edges per scatter block

typedef __attribute__((ext_vector_type(8))) short short8;   // 8 bf16 = 4 VGPRs
typedef __attribute__((ext_vector_type(4))) float f32x4;
typedef __attribute__((ext_vector_type(2))) _Float16 h16x2; // packed f16 pair

__device__ __forceinline__ float bf2f(uint32_t u) {
  return __uint_as_float(u << 16);
}
__device__ __forceinline__ uint32_t f2bf(float f) {  // round-to-nearest-even
  uint32_t x = __float_as_uint(f);
  return (x + 0x7FFFu + ((x >> 16) & 1u)) >> 16;
}

union H16 { _Float16 h; uint16_t u; };
union H2U { h16x2 h; uint32_t u; };

// f32 -> e5m2 byte (RNE via f16 then RNE-truncate mantissa to 2 bits)
__device__ __forceinline__ uint32_t f2e5m2(float f) {
  f = fminf(fmaxf(f, -30000.f), 30000.f);
  H16 cv;
  cv.h = (_Float16)f;
  uint32_t h = cv.u;
  uint32_t r = h + 0x7Fu + ((h >> 8) & 1u);
  return (r >> 8) & 0xFFu;
}

// e5m2 byte -> f32 (exact: e5m2 is truncated f16)
__device__ __forceinline__ float e5m2f(uint32_t b) {
  H16 cv;
  cv.u = (uint16_t)(b << 8);
  return (float)cv.h;
}

// ---------------- CSR build ----------------

// Block-aggregated, XCD-partitioned scatter. 4096 edges/block. (R10)
__global__ __launch_bounds__(256) void bucket_scatter(const int* __restrict__ src,
                                                      const int* __restrict__ dst,
                                                      int* __restrict__ bcur,
                                                      uint32_t* __restrict__ ebuf,
                                                      int nE, int nbuk) {
  uint32_t xcc;
  asm("s_getreg_b32 %0, hwreg(HW_REG_XCC_ID)" : "=s"(xcc));  // 0..7, wave-uniform
  __shared__ int lhist[1024];
  __shared__ int gbase[1024];
  int t = threadIdx.x;
  for (int i = t; i < nbuk; i += 256) lhist[i] = 0;
  __syncthreads();

  int e0 = blockIdx.x * TILE;
  int myd[16], mys[16], myrank[16];
#pragma unroll
  for (int j = 0; j < 16; ++j) {
    int e = e0 + t + j * 256;  // coalesced
    if (e < nE) {
      int d = dst[e];
      myd[j] = d;
      mys[j] = src[e];
      myrank[j] = atomicAdd(&lhist[d >> 7], 1);  // returns old -> local rank
    } else {
      myd[j] = -1;
    }
  }
  __syncthreads();
  for (int i = t; i < nbuk; i += 256) {
    int c = lhist[i];
    gbase[i] = c ? atomicAdd(&bcur[((i << 3) | (int)xcc) * 16], c) : 0;
  }
  __syncthreads();
#pragma unroll
  for (int j = 0; j < 16; ++j) {
    if (myd[j] >= 0) {
      int b = myd[j] >> 7;
      int pos = gbase[b] + myrank[j];
      if (pos < SUBCAP) {
        int sub = (b << 3) | (int)xcc;
        ebuf[(size_t)sub * SUBCAP + pos] =
            ((uint32_t)(myd[j] & 127) << 20) | (uint32_t)mys[j];
      }
    }
  }
}

// Fused hist + prefix + fill (R12) + side jobs: W cvt, pool zero (R14).
__global__ __launch_bounds__(256) void bucket_build(const uint32_t* __restrict__ ebuf,
                                                    const int* __restrict__ bcur,
                                                    int* __restrict__ deg,
                                                    float* __restrict__ dinv,
                                                    int* __restrict__ offs,
                                                    int* __restrict__ csr,
                                                    const float* __restrict__ W1,
                                                    const float* __restrict__ W2,
                                                    const float* __restrict__ W3,
                                                    uint16_t* __restrict__ WT,
                                                    float* __restrict__ pool,
                                                    int n, int nbuk) {
  int b = blockIdx.x;
  int base = b << 7;
  __shared__ int hist[128];
  __shared__ int pre[128];
  __shared__ int lcur[128];
  int t = threadIdx.x;

  // Side job 1: W1,W2,W3 fp32 [k][nn] -> WT bf16 [w][nn][k]  (grid-stride)
  for (int id = b * 256 + t; id < 3 * 16384; id += nbuk * 256) {
    int w = id >> 14;
    int rem = id & 16383;
    int k = rem >> 7, nn = rem & 127;
    const float* W = (w == 0) ? W1 : ((w == 1) ? W2 : W3);
    WT[w * 16384 + nn * 128 + k] = (uint16_t)f2bf(W[k * 128 + nn]);
  }
  // Side job 2: zero pool
  for (int id = b * 256 + t; id < 64 * 128; id += nbuk * 256) pool[id] = 0.f;

  if (t < 128) hist[t] = 0;
  __syncthreads();
  int cnts[8];
#pragma unroll
  for (int x = 0; x < 8; ++x) {
    int sub = (b << 3) | x;
    int cnt = min(bcur[sub * 16], SUBCAP);
    cnts[x] = cnt;
    const uint32_t* eb = ebuf + (size_t)sub * SUBCAP;
    for (int e = t; e < cnt; e += 256) atomicAdd(&hist[eb[e] >> 20], 1);
  }
  __syncthreads();
  if (t < 128) pre[t] = (hist[t] + 3) & ~3;  // ceil4 region sizes
  __syncthreads();
  for (int d = 1; d < 128; d <<= 1) {  // inclusive scan
    int v = (t >= d && t < 128) ? pre[t - d] : 0;
    __syncthreads();
    if (t < 128) pre[t] += v;
    __syncthreads();
  }
  if (t < 128) {
    int dg = hist[t];
    int start = b * CSRCAP + pre[t] - ((dg + 3) & ~3);  // 4-aligned
    lcur[t] = start;
    if (base + t < n) {
      deg[base + t] = dg;
      dinv[base + t] = rsqrtf((float)(dg + 1));  // +1 self-loop
      offs[base + t] = start;
    }
  }
  __syncthreads();
#pragma unroll
  for (int x = 0; x < 8; ++x) {
    int sub = (b << 3) | x;
    int cnt = cnts[x];
    const uint32_t* eb = ebuf + (size_t)sub * SUBCAP;
    for (int e = t; e < cnt; e += 256) {
      uint32_t ed = eb[e];
      int pos = atomicAdd(&lcur[ed >> 20], 1);
      csr[pos] = (int)((ed & 0xFFFFFu) << 7);  // byte offset into fp8 table
    }
  }
}

// ---------------- MFMA GEMM: bf16/fp32 in, fp8(e5m2) table out ----------------

template <bool F32IN>
__global__ __launch_bounds__(256) void gemm_mfma(const uint16_t* __restrict__ Xb,
                                                 const float* __restrict__ X32,
                                                 const uint16_t* __restrict__ WTb,
                                                 const float* __restrict__ dinv,
                                                 uint8_t* __restrict__ tab, int n) {
  __shared__ uint16_t sW[128 * 136];
  int t = threadIdx.x;
#pragma unroll
  for (int i = 0; i < 8; ++i) {
    int j = t + i * 256;
    int r = j >> 4, c = j & 15;
    float4 v = ((const float4*)WTb)[j];
    *(float4*)(sW + r * 136 + c * 8) = v;
  }
  __syncthreads();

  int wave = t >> 6, lane = t & 63;
  int quad = lane >> 4, l15 = lane & 15;
  int m = blockIdx.x * 64 + wave * 16 + l15;
  int mm = min(m, n - 1);

  short8 a[4];
#pragma unroll
  for (int kc = 0; kc < 4; ++kc) {
    if constexpr (F32IN) {
      const float* p = X32 + (size_t)mm * 128 + kc * 32 + quad * 8;
      float4 lo = *(const float4*)p;
      float4 hi = *(const float4*)(p + 4);
      a[kc] = (short8){(short)f2bf(lo.x), (short)f2bf(lo.y),
                       (short)f2bf(lo.z), (short)f2bf(lo.w),
                       (short)f2bf(hi.x), (short)f2bf(hi.y),
                       (short)f2bf(hi.z), (short)f2bf(hi.w)};
    } else {
      a[kc] = *(const short8*)(Xb + (size_t)mm * 128 + kc * 32 + quad * 8);
    }
  }

  f32x4 acc[8];
#pragma unroll
  for (int nn = 0; nn < 8; ++nn) acc[nn] = (f32x4){0.f, 0.f, 0.f, 0.f};

#pragma unroll
  for (int nn = 0; nn < 8; ++nn) {
    int nrow = nn * 16 + l15;
#pragma unroll
    for (int kc = 0; kc < 4; ++kc) {
      short8 b = *(const short8*)(sW + nrow * 136 + kc * 32 + quad * 8);
      acc[nn] = __builtin_amdgcn_mfma_f32_16x16x32_bf16(a[kc], b, acc[nn], 0, 0, 0);
    }
  }

  int mrow = blockIdx.x * 64 + wave * 16 + quad * 4;
#pragma unroll
  for (int r = 0; r < 4; ++r) {
    int row = mrow + r;
    if (row < n) {
      float dn = dinv[row];
#pragma unroll
      for (int nn = 0; nn < 8; ++nn) {
        tab[(size_t)row * 128 + nn * 16 + l15] = (uint8_t)f2e5m2(acc[nn][r] * dn);
      }
    }
  }
}

// ---------------- gather: half-wave per node, packed f16, int4 csr ----------------

__device__ __forceinline__ void acc_pk(uint32_t u, h16x2& a01, h16x2& a23) {
  H2U p01, p23;
  p01.u = __builtin_amdgcn_perm(u, 0u, 0x05010400u);  // (b0<<8)|(b1<<24)
  p23.u = __builtin_amdgcn_perm(u, 0u, 0x07010600u);  // (b2<<8)|(b3<<24)
  a01 += p01.h;
  a23 += p23.h;
}

__global__ __launch_bounds__(256) void gather_fused(const uint8_t* __restrict__ tab,
                                                    const int* __restrict__ csr,
                                                    const int* __restrict__ offs,
                                                    const int* __restrict__ deg,
                                                    const float* __restrict__ dinv,
                                                    const float* __restrict__ b,
                                                    uint16_t* __restrict__ out, int n) {
  int node = blockIdx.x * 8 + (threadIdx.x >> 5);
  if (node >= n) return;
  int l = threadIdx.x & 31;
  int c = l * 4;  // feature/byte offset within row
  const uint8_t* tabc = tab + c;
  int e0 = offs[node];             // 4-aligned by construction
  int e1 = e0 + deg[node];
  h16x2 a01 = (h16x2){(_Float16)0.f, (_Float16)0.f};
  h16x2 a23 = (h16x2){(_Float16)0.f, (_Float16)0.f};

  int e = e0;
  for (; e + 7 < e1; e += 8) {
    int4 ca = *(const int4*)(csr + e);
    int4 cb = *(const int4*)(csr + e + 4);
    uint32_t u[8];
    u[0] = *(const uint32_t*)(tabc + ca.x);
    u[1] = *(const uint32_t*)(tabc + ca.y);
    u[2] = *(const uint32_t*)(tabc + ca.z);
    u[3] = *(const uint32_t*)(tabc + ca.w);
    u[4] = *(const uint32_t*)(tabc + cb.x);
    u[5] = *(const uint32_t*)(tabc + cb.y);
    u[6] = *(const uint32_t*)(tabc + cb.z);
    u[7] = *(const uint32_t*)(tabc + cb.w);
#pragma unroll
    for (int j = 0; j < 8; ++j) acc_pk(u[j], a01, a23);
  }
  if (e + 3 < e1) {
    int4 ca = *(const int4*)(csr + e);
    uint32_t u[4];
    u[0] = *(const uint32_t*)(tabc + ca.x);
    u[1] = *(const uint32_t*)(tabc + ca.y);
    u[2] = *(const uint32_t*)(tabc + ca.z);
    u[3] = *(const uint32_t*)(tabc + ca.w);
#pragma unroll
    for (int j = 0; j < 4; ++j) acc_pk(u[j], a01, a23);
    e += 4;
  }
  for (; e < e1; ++e) acc_pk(*(const uint32_t*)(tabc + csr[e]), a01, a23);

  float a0 = (float)a01.x, a1 = (float)a01.y;
  float a2 = (float)a23.x, a3 = (float)a23.y;

  float dn = dinv[node];
  uint32_t uh = *(const uint32_t*)(tabc + node * 128);  // self-loop
  float4 bb = *(const float4*)(b + c);
  float o0 = (a0 + e5m2f(uh & 0xFFu)) * dn + bb.x;
  float o1 = (a1 + e5m2f((uh >> 8) & 0xFFu)) * dn + bb.y;
  float o2 = (a2 + e5m2f((uh >> 16) & 0xFFu)) * dn + bb.z;
  float o3 = (a3 + e5m2f(uh >> 24)) * dn + bb.w;
  o0 = o0 > 0.f ? o0 : expm1f(o0);
  o1 = o1 > 0.f ? o1 : expm1f(o1);
  o2 = o2 > 0.f ? o2 : expm1f(o2);
  o3 = o3 > 0.f ? o3 : expm1f(o3);
  uint2 po;
  po.x = f2bf(o0) | (f2bf(o1) << 16);
  po.y = f2bf(o2) | (f2bf(o3) << 16);
  *(uint2*)(out + (size_t)node * 128 + c) = po;
}

// ---------------- pooling + head ----------------

__global__ __launch_bounds__(128) void pool_kernel(const uint16_t* __restrict__ h,
                                                   const int* __restrict__ batch,
                                                   float* __restrict__ pool, int n) {
  int f = threadIdx.x;
  int i0 = blockIdx.x * 64;
  int iend = min(i0 + 64, n);
  __shared__ int sb[64];
  if (threadIdx.x < 64 && i0 + threadIdx.x < n) sb[threadIdx.x] = batch[i0 + threadIdx.x];
  __syncthreads();
  float acc = 0.f;
  int cur = sb[0];
  for (int i = i0; i < iend; ++i) {
    int g = sb[i - i0];
    if (g != cur) {
      atomicAdd(&pool[cur * 128 + f], acc);
      acc = 0.f;
      cur = g;
    }
    acc += bf2f((uint32_t)h[(size_t)i * 128 + f]);
  }
  atomicAdd(&pool[cur * 128 + f], acc);
}

// One wave per graph: cnt (binary search), z_j = relu(g.Wc1_j + bc1_j),
// logit = shfl-reduce(z_j * Wc2_j) + bc2. Coalesced Wc1 reads (lane = j).
__global__ __launch_bounds__(64) void classifier_kernel(const float* __restrict__ pool,
                                                        const int* __restrict__ batch,
                                                        const float* __restrict__ Wc1,
                                                        const float* __restrict__ bc1,
                                                        const float* __restrict__ Wc2,
                                                        const float* __restrict__ bc2,
                                                        float* __restrict__ out, int n) {
  int g = blockIdx.x;   // graph id, 0..63
  int j = threadIdx.x;  // hidden unit, 0..63
  __shared__ float sg[128];

  // cnt for this graph (all lanes redundantly; 2 binary searches)
  int lo = 0, hi = n;
  while (lo < hi) {
    int mid = (lo + hi) >> 1;
    if (batch[mid] < g) lo = mid + 1; else hi = mid;
  }
  int a = lo;
  lo = 0; hi = n;
  while (lo < hi) {
    int mid = (lo + hi) >> 1;
    if (batch[mid] < g + 1) lo = mid + 1; else hi = mid;
  }
  float inv = 1.f / (float)max(lo - a, 1);

  sg[j] = pool[g * 128 + j] * inv;
  sg[j + 64] = pool[g * 128 + j + 64] * inv;
  __syncthreads();

  float acc = bc1[j];
#pragma unroll 4
  for (int k = 0; k < 128; ++k) acc += sg[k] * Wc1[k * 64 + j];  // coalesced in j
  float z = fmaxf(acc, 0.f);

  float v = z * Wc2[j];
#pragma unroll
  for (int m = 32; m > 0; m >>= 1) v += __shfl_xor(v, m, 64);
  if (j == 0) out[g] = 1.f / (1.f + expf(-(v + bc2[0])));
}

extern "C" void kernel_launch(void* const* d_in, const int* in_sizes, int n_in,
                              void* d_out, int out_size, void* d_ws, size_t ws_size,
                              hipStream_t stream) {
  const float* x   = (const float*)d_in[0];
  const int* ei    = (const int*)d_in[1];
  const int* batch = (const int*)d_in[2];
  const float* W1  = (const float*)d_in[3];
  const float* b1  = (const float*)d_in[4];
  const float* W2  = (const float*)d_in[5];
  const float* b2  = (const float*)d_in[6];
  const float* W3  = (const float*)d_in[7];
  const float* b3  = (const float*)d_in[8];
  const float* Wc1 = (const float*)d_in[9];
  const float* bc1 = (const float*)d_in[10];
  const float* Wc2 = (const float*)d_in[11];
  const float* bc2 = (const float*)d_in[12];

  int n  = in_sizes[2];
  int nE = in_sizes[1] / 2;
  const int* src = ei;
  const int* dst = ei + nE;
  int nbuk = (n + 127) >> 7;  // 128-node dst buckets

  // Workspace (~68 MB). All segment element counts multiples of 4.
  uint8_t*  tab  = (uint8_t*)d_ws;                      // fp8 table [n*128]
  uint16_t* bufO = (uint16_t*)(tab + (size_t)n * 128);  // bf16 layer buf [n*128]
  float* dinv    = (float*)(bufO + (size_t)n * 128);
  int*   deg     = (int*)(dinv + n);
  int*   offs    = deg + n;                             // [n+4]
  int*   bcur    = offs + n + 4;                        // [nbuk*8*16] padded
  int*   csr     = bcur + nbuk * 8 * 16;                // [nbuk*CSRCAP]
  uint32_t* ebuf = (uint32_t*)(csr + (size_t)nbuk * CSRCAP);  // [nbuk*8*SUBCAP]
  uint16_t* WT   = (uint16_t*)(ebuf + (size_t)nbuk * 8 * SUBCAP);
  float* pool    = (float*)(WT + 3 * 16384);
  float* out     = (float*)d_out;

  hipMemsetAsync(bcur, 0, (size_t)nbuk * 8 * 16 * sizeof(int), stream);
  bucket_scatter<<<(nE + TILE - 1) / TILE, 256, 0, stream>>>(src, dst, bcur, ebuf, nE, nbuk);
  bucket_build<<<nbuk, 256, 0, stream>>>(ebuf, bcur, deg, dinv, offs, csr,
                                         W1, W2, W3, WT, pool, n, nbuk);

  const float* bs[3] = {b1, b2, b3};
  for (int l = 0; l < 3; ++l) {
    if (l == 0)
      gemm_mfma<true><<<(n + 63) / 64, 256, 0, stream>>>(nullptr, x, WT, dinv, tab, n);
    else
      gemm_mfma<false><<<(n + 63) / 64, 256, 0, stream>>>(bufO, nullptr, WT + l * 16384, dinv, tab, n);
    gather_fused<<<(n + 7) / 8, 256, 0, stream>>>(tab, csr, offs, deg, dinv, bs[l], bufO, n);
  }

  pool_kernel<<<(n + 63) / 64, 128, 0, stream>>>(bufO, batch, pool, n);
  classifier_kernel<<<64, 64, 0, stream>>>(pool, batch, Wc1, bc1, Wc2, bc2, out, n);
}